// Round 6
// baseline (818.054 us; speedup 1.0000x reference)
//
#include <hip/hip_runtime.h>
#include <hip/hip_bf16.h>
#include <stdint.h>

// ---------------------------------------------------------------------------
// OffsetHead: pointwise MLP (64->32->16->3) + revoxelize (unique rows + means)
//
// R8 changes vs R7:
//   * k_mlp: 2 rows/thread (i, i+256), loads in-loop (compiler sinks them;
//     R3's spill came from explicit prefetch temps), __launch_bounds__(256,4)
//     caps VGPR at 128. Halves wave count and amortizes each scalar weight
//     fetch across 2 rows (8 FMAs/fetch). Per-row FMA order unchanged ->
//     bitwise-identical offsets.
//   * k_passA packed: 4 buckets per wave in 16-lane segments (seg_sort<16>
//     already segment-local; ballot masks cut to 16-bit). Buckets with
//     cnt>16 (~1e-3 of buckets; deterministically <= 58823 <= biglist cap
//     65536) go to a list processed by full-wave fallback k_passA_big.
//     139k waves -> 34.8k + ~0.2k.
// ---------------------------------------------------------------------------

#define TPB 256
#define NB 139264          // 2048 * 68
#define NCHUNK 544         // NB / 256
#define BIGCAP 65536       // >= 1e6/17 max possible cnt>16 buckets
typedef unsigned long long ull;
typedef float vf4 __attribute__((ext_vector_type(4)));

// --------------------------------------------------------------------------
// Epilogue: mask, store offsets, build key, insert into bucket.
// --------------------------------------------------------------------------
__device__ __forceinline__ void epilogue(
    int i, float o0, float o1, float o2,
    const int* __restrict__ coords, const unsigned char* __restrict__ mask,
    float* __restrict__ out_off, ull* __restrict__ slots,
    unsigned int* __restrict__ cursor)
{
    float m = mask[i] ? 1.0f : 0.0f;
    o0 *= m; o1 *= m; o2 *= m;
    out_off[(size_t)3 * i + 0] = o0;
    out_off[(size_t)3 * i + 1] = o1;
    out_off[(size_t)3 * i + 2] = o2;

    // Key build: round-half-even (rintf == v_rndne, matches jnp.round)
    int4 c = ((const int4*)coords)[i];
    int r1 = (int)rintf(o0), r2 = (int)rintf(o1), r3 = (int)rintf(o2);
    int c1u = c.y + r1, c2u = c.z + r2, c3u = c.w + r3;
    int c1s = min(max(c1u + 1024, 0), 8191);
    int c2s = min(max(c2u + 1024, 0), 8191);
    int c3s = min(max(c3u + 1024, 0), 8191);
    int bin1 = min(max((c1u + 64) >> 5, 0), 67);
    int b = c.x * 68 + bin1;
    ull row39 = ((ull)c1s << 26) | ((ull)c2s << 13) | (ull)c3s;
    ull packed = (row39 << 20) | (ull)(unsigned int)i;
    unsigned int j = atomicAdd(&cursor[b], 1u);
    if (j < 64u) slots[(size_t)b * 64 + j] = packed;
}

// --------------------------------------------------------------------------
// MLP, 2 rows per thread.
// --------------------------------------------------------------------------
__global__ __launch_bounds__(256, 4) void k_mlp(
    const float* __restrict__ feats, const int* __restrict__ coords,
    const unsigned char* __restrict__ mask,
    const float* __restrict__ W1, const float* __restrict__ b1,
    const float* __restrict__ W2, const float* __restrict__ b2,
    const float* __restrict__ W3, const float* __restrict__ b3,
    float* __restrict__ out_off, ull* __restrict__ slots,
    unsigned int* __restrict__ cursor, int n)
{
    int i0 = blockIdx.x * (2 * TPB) + threadIdx.x;
    if (i0 >= n) return;
    int i1 = i0 + TPB;
    bool v1 = (i1 < n);

    const vf4* fa = (const vf4*)(feats + (size_t)i0 * 64);
    const vf4* fb = (const vf4*)(feats + (size_t)(v1 ? i1 : i0) * 64);

    // Layer 1: ascending-k FMA accumulation, bias added AFTER (match XLA GEMM).
    // Weights via uniform (scalar) loads; each fetch feeds both rows.
    float h1a[32], h1b[32];
    #pragma unroll
    for (int j = 0; j < 32; ++j) { h1a[j] = 0.0f; h1b[j] = 0.0f; }
    #pragma unroll
    for (int kc = 0; kc < 16; ++kc) {
        vf4 av = fa[kc];
        vf4 bv = fb[kc];
        #pragma unroll
        for (int d = 0; d < 4; ++d) {
            float xa = (d == 0) ? av.x : (d == 1) ? av.y : (d == 2) ? av.z : av.w;
            float xb = (d == 0) ? bv.x : (d == 1) ? bv.y : (d == 2) ? bv.z : bv.w;
            const float* wr = W1 + (kc * 4 + d) * 32;
            #pragma unroll
            for (int j = 0; j < 32; j += 4) {
                float4 w = *(const float4*)(wr + j);
                h1a[j + 0] = fmaf(xa, w.x, h1a[j + 0]);
                h1a[j + 1] = fmaf(xa, w.y, h1a[j + 1]);
                h1a[j + 2] = fmaf(xa, w.z, h1a[j + 2]);
                h1a[j + 3] = fmaf(xa, w.w, h1a[j + 3]);
                h1b[j + 0] = fmaf(xb, w.x, h1b[j + 0]);
                h1b[j + 1] = fmaf(xb, w.y, h1b[j + 1]);
                h1b[j + 2] = fmaf(xb, w.z, h1b[j + 2]);
                h1b[j + 3] = fmaf(xb, w.w, h1b[j + 3]);
            }
        }
    }
    #pragma unroll
    for (int j = 0; j < 32; ++j) {
        h1a[j] = fmaxf(h1a[j] + b1[j], 0.0f);
        h1b[j] = fmaxf(h1b[j] + b1[j], 0.0f);
    }

    // Layer 2
    float h2a[16], h2b[16];
    #pragma unroll
    for (int j = 0; j < 16; ++j) { h2a[j] = 0.0f; h2b[j] = 0.0f; }
    #pragma unroll
    for (int k = 0; k < 32; ++k) {
        float xa = h1a[k], xb = h1b[k];
        const float* wr = W2 + k * 16;
        #pragma unroll
        for (int j = 0; j < 16; j += 4) {
            float4 w = *(const float4*)(wr + j);
            h2a[j + 0] = fmaf(xa, w.x, h2a[j + 0]);
            h2a[j + 1] = fmaf(xa, w.y, h2a[j + 1]);
            h2a[j + 2] = fmaf(xa, w.z, h2a[j + 2]);
            h2a[j + 3] = fmaf(xa, w.w, h2a[j + 3]);
            h2b[j + 0] = fmaf(xb, w.x, h2b[j + 0]);
            h2b[j + 1] = fmaf(xb, w.y, h2b[j + 1]);
            h2b[j + 2] = fmaf(xb, w.z, h2b[j + 2]);
            h2b[j + 3] = fmaf(xb, w.w, h2b[j + 3]);
        }
    }
    #pragma unroll
    for (int j = 0; j < 16; ++j) {
        h2a[j] = fmaxf(h2a[j] + b2[j], 0.0f);
        h2b[j] = fmaxf(h2b[j] + b2[j], 0.0f);
    }

    // Layer 3
    float o0a = 0.0f, o1a = 0.0f, o2a = 0.0f;
    float o0b = 0.0f, o1b = 0.0f, o2b = 0.0f;
    #pragma unroll
    for (int k = 0; k < 16; ++k) {
        float xa = h2a[k], xb = h2b[k];
        float w0 = W3[k * 3 + 0], w1 = W3[k * 3 + 1], w2 = W3[k * 3 + 2];
        o0a = fmaf(xa, w0, o0a);
        o1a = fmaf(xa, w1, o1a);
        o2a = fmaf(xa, w2, o2a);
        o0b = fmaf(xb, w0, o0b);
        o1b = fmaf(xb, w1, o1b);
        o2b = fmaf(xb, w2, o2b);
    }
    o0a += b3[0]; o1a += b3[1]; o2a += b3[2];
    o0b += b3[0]; o1b += b3[1]; o2b += b3[2];

    epilogue(i0, o0a, o1a, o2a, coords, mask, out_off, slots, cursor);
    if (v1)
        epilogue(i1, o0b, o1b, o2b, coords, mask, out_off, slots, cursor);
}

// --------------------------------------------------------------------------
// Segment-local bitonic sort of W elements (W-aligned lane groups).
// For k == W the (k & (W-1)) term is 0 -> final merge ascending in every
// W-lane group simultaneously.
// --------------------------------------------------------------------------
template<int W>
__device__ inline ull seg_sort(ull v, int lane)
{
    #pragma unroll
    for (int k = 2; k <= W; k <<= 1) {
        #pragma unroll
        for (int j = k >> 1; j > 0; j >>= 1) {
            ull o = __shfl_xor(v, j, 64);
            bool up = ((lane & (k & (W - 1))) == 0);
            bool lower = ((lane & j) == 0);
            ull mn = (v < o) ? v : o;
            ull mx = (v < o) ? o : v;
            v = (up == lower) ? mn : mx;
        }
    }
    return v;
}

// --------------------------------------------------------------------------
// Full-wave pass-A body (W = 32 or 64), for big buckets.
// --------------------------------------------------------------------------
template<int W>
__device__ inline void passA_body(
    ull* __restrict__ slots, unsigned int* __restrict__ ucnt,
    unsigned int* __restrict__ inv_bits, int b, int lane, unsigned int cnt)
{
    ull v = (lane < (int)cnt) ? slots[(size_t)b * 64 + lane] : ~0ULL;
    v = seg_sort<W>(v, lane);

    ull row = v >> 20;
    unsigned int idx = (unsigned int)(v & 0xFFFFFULL);
    ull prev = __shfl_up(row, 1, 64);
    bool head = (lane < (int)cnt) && ((lane == 0) || (row != prev));
    ull hm = __ballot(head);
    ull le = (lane == 63) ? ~0ULL : ((1ULL << (lane + 1)) - 1ULL);
    int lrank = __popcll(hm & le) - 1;
    if (lane == 0) ucnt[b] = (unsigned int)__popcll(hm);
    if (lane < (int)cnt)
        inv_bits[idx] = (unsigned int)(b * 64 + lrank);

    int c3s = (int)(row & 0x1FFFULL);
    int c2s = (int)((row >> 13) & 0x1FFFULL);
    int c1s = (int)(row >> 26);
    ull sum = (lane < (int)cnt)
        ? ((1ULL << 57) | ((ull)c1s << 38) | ((ull)c2s << 19) | (ull)c3s)
        : 0ULL;
    ull P = sum;
    #pragma unroll
    for (int d = 1; d < W; d <<= 1) {
        ull t = __shfl_up(P, d, 64);
        if (lane >= d) P += t;
    }
    ull gt = hm & ~le;
    int tpos = gt ? (__ffsll((long long)gt) - 2) : ((int)cnt - 1);
    ull Pt = __shfl(P, tpos, 64);
    int hsrc = (lane > 0) ? lane - 1 : 0;
    ull Ph = __shfl(P, hsrc, 64);
    if (lane == 0) Ph = 0ULL;
    if (head) slots[(size_t)b * 64 + lrank] = Pt - Ph;
}

// --------------------------------------------------------------------------
// Packed pass A: 4 buckets per wave, 16-lane segments (cnt <= 16).
// Buckets with cnt > 16 are appended to biglist for k_passA_big.
// --------------------------------------------------------------------------
__global__ __launch_bounds__(256) void k_passA(
    ull* __restrict__ slots, const unsigned int* __restrict__ cursor,
    unsigned int* __restrict__ ucnt, float* __restrict__ out_inv,
    unsigned int* __restrict__ bigcount, int* __restrict__ biglist)
{
    int lane = threadIdx.x & 63;
    int seg = lane >> 4;            // 0..3
    int sl = lane & 15;             // lane within segment
    int wv = threadIdx.x >> 6;      // wave in block
    int b = blockIdx.x * 16 + wv * 4 + seg;
    unsigned int cnt = cursor[b];
    if (cnt > 64u) cnt = 64u;
    unsigned int* inv_bits = (unsigned int*)out_inv;

    if (cnt == 0u) {
        if (sl == 0) ucnt[b] = 0u;
        return;
    }
    if (cnt > 16u) {
        if (sl == 0) {
            unsigned int j = atomicAdd(bigcount, 1u);
            if (j < BIGCAP) biglist[j] = b;
        }
        return;
    }

    ull v = (sl < (int)cnt) ? slots[(size_t)b * 64 + sl] : ~0ULL;
    v = seg_sort<16>(v, lane);      // independent sort in each 16-lane group

    ull row = v >> 20;
    unsigned int idx = (unsigned int)(v & 0xFFFFFULL);
    ull prev = __shfl_up(row, 1, 64);           // cross-segment read unused (sl==0)
    bool head = (sl < (int)cnt) && ((sl == 0) || (row != prev));
    ull hm = __ballot(head);
    unsigned int sm = (unsigned int)((hm >> (seg << 4)) & 0xFFFFULL);
    unsigned int le16 = (1u << (sl + 1)) - 1u;
    int lrank = __popc(sm & le16) - 1;
    if (sl == 0) ucnt[b] = (unsigned int)__popc(sm);
    if (sl < (int)cnt)
        inv_bits[idx] = (unsigned int)(b * 64 + lrank);

    int c3s = (int)(row & 0x1FFFULL);
    int c2s = (int)((row >> 13) & 0x1FFFULL);
    int c1s = (int)(row >> 26);
    ull sum = (sl < (int)cnt)
        ? ((1ULL << 57) | ((ull)c1s << 38) | ((ull)c2s << 19) | (ull)c3s)
        : 0ULL;
    ull P = sum;
    #pragma unroll
    for (int d = 1; d < 16; d <<= 1) {
        ull t = __shfl_up(P, d, 64);
        if (sl >= d) P += t;        // sl>=d => source lane in same segment
    }
    unsigned int gt = sm & ~le16;
    int tposl = gt ? (__ffs((int)gt) - 2) : ((int)cnt - 1);
    ull Pt = __shfl(P, (seg << 4) + tposl, 64);
    int hsrc = (sl > 0) ? lane - 1 : lane;
    ull Ph = __shfl(P, hsrc, 64);
    if (sl == 0) Ph = 0ULL;
    if (head) slots[(size_t)b * 64 + lrank] = Pt - Ph;
}

// Fallback for buckets with 16 < cnt <= 64: one full wave per bucket.
__global__ __launch_bounds__(256) void k_passA_big(
    ull* __restrict__ slots, const unsigned int* __restrict__ cursor,
    unsigned int* __restrict__ ucnt, float* __restrict__ out_inv,
    const unsigned int* __restrict__ bigcount, const int* __restrict__ biglist)
{
    int lane = threadIdx.x & 63;
    int wave = blockIdx.x * 4 + (threadIdx.x >> 6);
    int nwaves = gridDim.x * 4;
    unsigned int bc = *bigcount;
    if (bc > BIGCAP) bc = BIGCAP;
    unsigned int* inv_bits = (unsigned int*)out_inv;
    for (unsigned int t = (unsigned int)wave; t < bc; t += (unsigned int)nwaves) {
        int b = biglist[t];
        unsigned int cnt = cursor[b];
        if (cnt > 64u) cnt = 64u;
        if (cnt <= 32u) passA_body<32>(slots, ucnt, inv_bits, b, lane, cnt);
        else            passA_body<64>(slots, ucnt, inv_bits, b, lane, cnt);
    }
}

// Scan level 1: exclusive scan within 256-entry chunks.
__global__ __launch_bounds__(256) void k_scanA(
    const unsigned int* __restrict__ ucnt, unsigned int* __restrict__ lstart,
    unsigned int* __restrict__ chsum)
{
    __shared__ unsigned int s[256];
    int tid = threadIdx.x;
    int g = blockIdx.x * 256 + tid;
    unsigned int v = ucnt[g];
    s[tid] = v;
    __syncthreads();
    for (int ofs = 1; ofs < 256; ofs <<= 1) {
        unsigned int t = (tid >= ofs) ? s[tid - ofs] : 0u;
        __syncthreads();
        s[tid] += t;
        __syncthreads();
    }
    lstart[g] = s[tid] - v;
    if (tid == 255) chsum[blockIdx.x] = s[255];
}

// Scan level 2: exclusive scan of chunk sums (in place).
__global__ __launch_bounds__(1024) void k_scanB(unsigned int* __restrict__ chsum)
{
    __shared__ unsigned int s[1024];
    int tid = threadIdx.x;
    unsigned int v = (tid < NCHUNK) ? chsum[tid] : 0u;
    s[tid] = v;
    __syncthreads();
    for (int ofs = 1; ofs < 1024; ofs <<= 1) {
        unsigned int t = (tid >= ofs) ? s[tid - ofs] : 0u;
        __syncthreads();
        s[tid] += t;
        __syncthreads();
    }
    if (tid < NCHUNK) chsum[tid] = s[tid] - v;
}

// Final: per element, resolve global rank AND write the cluster mean.
// All members of a run write the identical float4 -> idempotent, race-free.
__global__ __launch_bounds__(256) void k_final(
    float* __restrict__ out_inv, float* __restrict__ out_oc,
    const ull* __restrict__ slots, const unsigned int* __restrict__ lstart,
    const unsigned int* __restrict__ chbase, int n)
{
    int i = blockIdx.x * TPB + threadIdx.x;
    if (i >= n) return;
    unsigned int q = ((const unsigned int*)out_inv)[i];
    unsigned int b = q >> 6, lr = q & 63u;
    if (b >= NB) b = NB - 1;                    // overflow hardening (no OOB)
    unsigned int r = chbase[b >> 8] + lstart[b] + lr;
    out_inv[i] = (float)r;
    if (r < (unsigned int)n) {
        ull run = slots[(size_t)b * 64 + lr];
        int rc = (int)(run >> 57);
        int s1 = (int)((run >> 38) & 0x7FFFFULL) - 1024 * rc;
        int s2 = (int)((run >> 19) & 0x7FFFFULL) - 1024 * rc;
        int s3 = (int)(run & 0x7FFFFULL) - 1024 * rc;
        float fc = (float)rc;
        float4 o;
        o.x = (float)(b / 68u);                 // dim0 unchanged -> exact mean
        o.y = truncf((float)s1 / fc);
        o.z = truncf((float)s2 / fc);
        o.w = truncf((float)s3 / fc);
        ((float4*)out_oc)[r] = o;
    }
}

extern "C" void kernel_launch(void* const* d_in, const int* in_sizes, int n_in,
                              void* d_out, int out_size, void* d_ws, size_t ws_size,
                              hipStream_t stream)
{
    const float*         feats  = (const float*)d_in[0];
    const int*           coords = (const int*)d_in[1];
    const unsigned char* mask   = (const unsigned char*)d_in[2];
    const float* W1 = (const float*)d_in[3];
    const float* b1 = (const float*)d_in[4];
    const float* W2 = (const float*)d_in[5];
    const float* b2 = (const float*)d_in[6];
    const float* W3 = (const float*)d_in[7];
    const float* b3 = (const float*)d_in[8];

    int n = in_sizes[1] / 4;  // coords is [N,4]

    char* ws = (char*)d_ws;
    ull*          slots    = (ull*)ws;                                   // NB*64*8
    unsigned int* cursor   = (unsigned int*)(ws + (size_t)NB * 64 * 8);  // NB*4
    unsigned int* bigcount = cursor + NB;                                // 4 (zeroed with cursor)
    unsigned int* ucnt     = bigcount + 1;                               // NB*4
    unsigned int* lstart   = ucnt + NB;                                  // NB*4
    unsigned int* chsum    = lstart + NB;                                // NCHUNK*4
    int*          biglist  = (int*)(chsum + NCHUNK);                     // BIGCAP*4

    float* out     = (float*)d_out;
    float* out_off = out;                  // [N,3] offsets (float32)
    float* out_oc  = out + (size_t)3 * n;  // [N,4] out_coords (as float values)
    float* out_inv = out + (size_t)7 * n;  // [N]   inv (as float values)

    hipMemsetAsync(cursor, 0, (size_t)(NB + 1) * sizeof(unsigned int), stream);
    hipMemsetAsync(out_oc, 0, (size_t)4 * n * sizeof(float), stream);

    int nb256 = (n + TPB - 1) / TPB;
    int nb512 = (n + 2 * TPB - 1) / (2 * TPB);

    k_mlp<<<nb512, TPB, 0, stream>>>(feats, coords, mask, W1, b1, W2, b2, W3, b3,
                                     out_off, slots, cursor, n);
    k_passA<<<NB / 16, TPB, 0, stream>>>(slots, cursor, ucnt, out_inv,
                                         bigcount, biglist);
    k_passA_big<<<64, TPB, 0, stream>>>(slots, cursor, ucnt, out_inv,
                                        bigcount, biglist);
    k_scanA<<<NCHUNK, 256, 0, stream>>>(ucnt, lstart, chsum);
    k_scanB<<<1, 1024, 0, stream>>>(chsum);
    k_final<<<nb256, TPB, 0, stream>>>(out_inv, out_oc, slots, lstart, chsum, n);
}